// Round 18
// baseline (231.402 us; speedup 1.0000x reference)
//
#include <hip/hip_runtime.h>

// LightplaneSplatter: trilinear scatter-splat of per-ray encodings (C=16)
// into a (1,128,128,128,16) fp32 grid.
//
// Round 18: z-sort moved into scatter; accum = pure walk + flush.
//   Keys are (bin, z-bucket): key = bin*9 + zb, 36864 cursors. Scatter
//   emits records z-sorted within each bin, so accum's in-kernel staging +
//   9-bucket LDS histogram + placement phase is deleted; bucket boundaries
//   come straight from offsets[]. accum walks recs directly from global
//   (wave-uniform broadcast loads, R17's verbatim 4-deep ping-pong walk),
//   LDS 49.6->32.8 KB => 4 blocks/CU (100% wave cap). count_kernel becomes
//   scatter's twin (template<WRITE>): run-aggregated global atomics, no
//   LDS histogram.

#define NS   64
#define NSI  8
#define ST   (NS + NSI)   // 72
#define GD   128
#define GH   128
#define GW   128
#define GC   16
#define DISP_INF 1e-4f

#define NTT   16                    // tiles per axis (8 points each)
#define NBINS (NTT * NTT * NTT)     // 4096
#define NKEYS (NBINS * 9)           // 36864 (bin x z-bucket)
#define TILE_FL (8 * 8 * 8 * GC)    // 8192 floats = 32 KB
#define CHK   1024                  // samples per chunk
#define MULTI_FLAG 0x80000000u
#define ACC_THREADS 512             // 8 waves, one z-layer each

// ---------------------------------------------------------------------------
__device__ __forceinline__ bool compute_sample(
    const float* __restrict__ dirs, const float* __restrict__ orig,
    const float* __restrict__ nearv, const float* __restrict__ farv,
    int ray, int s,
    int& ix, int& iy, int& iz, float& fx, float& fy, float& fz)
{
    float nr = nearv[ray], fr = farv[ray];
    float t;
    if (s < NS) {
        float frac = ((float)s + 0.5f) * (1.0f / (float)NS);
        t = nr + (fr - nr) * frac;
    } else {
        float j    = (float)(s - NS + 1) * (1.0f / (float)NSI);
        float invf = 1.0f / fr;
        float disp = invf + (DISP_INF - invf) * j;
        t = 1.0f / disp;
    }
    float px = orig[ray*3+0] + t * dirs[ray*3+0];
    float py = orig[ray*3+1] + t * dirs[ray*3+1];
    float pz = orig[ray*3+2] + t * dirs[ray*3+2];
    float vx = (px + 1.0f) * 0.5f * 127.0f;
    float vy = (py + 1.0f) * 0.5f * 127.0f;
    float vz = (pz + 1.0f) * 0.5f * 127.0f;
    float bx = floorf(vx), by = floorf(vy), bz = floorf(vz);
    fx = vx - bx; fy = vy - by; fz = vz - bz;
    ix = (int)bx; iy = (int)by; iz = (int)bz;
    return !(ix < -1 || ix > GW - 1 ||
             iy < -1 || iy > GH - 1 ||
             iz < -1 || iz > GD - 1);
}

// Tile range touched by base cell i along one axis (i in [-1, 127]).
__device__ __forceinline__ void tile_range(int i, int& t0, int& t1)
{
    t0 = (i < 0 ? 0 : i) >> 3;
    t1 = (i + 1 > 127 ? 127 : i + 1) >> 3;
}

// ---------------------------------------------------------------------------
// Passes A (WRITE=false: count) and C (WRITE=true: scatter), shared body.
// Per footprint copy: key = bin*9 + zb. Wave-run aggregation: leader does one
// atomicAdd(cursor[key], runLen); for scatter, lanes write contiguous slots.
// Record: float4 { uint pack = ray<<12 | zb<<8 | (ly0+1)<<4 | (lx0+1),
//                  fx, fy, fz }.
template<bool WRITE>
__global__ __launch_bounds__(256) void bin_kernel(
    const float* __restrict__ dirs, const float* __restrict__ orig,
    const float* __restrict__ nearv, const float* __restrict__ farv,
    int* __restrict__ cursor, float4* __restrict__ recs, int total, int cap)
{
    int idx  = blockIdx.x * 256 + threadIdx.x;
    int lane = threadIdx.x & 63;
    bool act = (idx < total);

    int ix = 0, iy = 0, iz = 0; float fx = 0.f, fy = 0.f, fz = 0.f;
    int tx0 = 0, tx1 = -1, ty0 = 0, ty1 = -1, tz0 = 0, tz1 = -1;
    int ray = 0;
    if (act) {
        ray = idx / ST;
        int s = idx - ray * ST;
        if (compute_sample(dirs, orig, nearv, farv, ray, s, ix, iy, iz, fx, fy, fz)) {
            tile_range(ix, tx0, tx1);
            tile_range(iy, ty0, ty1);
            tile_range(iz, tz0, tz1);
        }
    }

    #pragma unroll
    for (int kz = 0; kz < 2; ++kz)
    #pragma unroll
    for (int ky = 0; ky < 2; ++ky)
    #pragma unroll
    for (int kx = 0; kx < 2; ++kx) {
        int tzi = tz0 + kz, tyi = ty0 + ky, txi = tx0 + kx;
        bool valid = (tzi <= tz1 && tyi <= ty1 && txi <= tx1);
        int zb  = iz - (tzi << 3) + 1;          // in [0,8] when valid
        int key = valid ? ((tzi * NTT + tyi) * NTT + txi) * 9 + zb : -1;

        // Run detection: leader = first lane of a maximal same-key run.
        int prev = __shfl_up(key, 1, 64);
        bool leader = (lane == 0) || (key != prev);
        unsigned long long lm = __ballot(leader);
        unsigned long long below = lm & ((2ull << lane) - 1ull);
        int lead = 63 - __clzll(below);

        int base = 0;
        if (leader && key >= 0) {
            unsigned long long rest = (lane == 63) ? 0ull : (lm >> (lane + 1));
            int next = rest ? (lane + 1 + (__ffsll((long long)rest) - 1)) : 64;
            base = atomicAdd(&cursor[key], next - lane);
        }
        if (WRITE) {
            base = __shfl(base, lead, 64);
            if (key >= 0) {
                int slot = base + (lane - lead);
                if (slot < cap) {
                    unsigned int pk = ((unsigned int)ray << 12)
                                    | ((unsigned int)zb << 8)
                                    | ((unsigned int)(iy - (tyi << 3) + 1) << 4)
                                    |  (unsigned int)(ix - (txi << 3) + 1);
                    recs[slot] = make_float4(__uint_as_float(pk), fx, fy, fz);
                }
            }
        }
    }
}

// ---------------------------------------------------------------------------
// Pass B: scan 36864 key-counts -> offsets/cursor; emit per-bin chunk table.
__global__ __launch_bounds__(256) void scan_kernel(
    const int* __restrict__ counts, int* __restrict__ offsets,
    int* __restrict__ cursor, unsigned int* __restrict__ chunk_info,
    int* __restrict__ nck)
{
    __shared__ int p1[256], p2[256];
    const int BPT = NBINS / 256;  // 16 bins (144 keys) per thread
    int tid = threadIdx.x;
    int b0 = tid * BPT;
    int s1 = 0, s2 = 0;
    for (int i = 0; i < BPT; ++i) {
        int bc = 0;
        for (int j = 0; j < 9; ++j) bc += counts[(b0 + i) * 9 + j];
        s1 += bc;
        s2 += (bc + CHK - 1) / CHK;
    }
    p1[tid] = s1; p2[tid] = s2;
    __syncthreads();
    if (tid == 0) {
        int a1 = 0, a2 = 0;
        for (int i = 0; i < 256; ++i) {
            int v1 = p1[i], v2 = p2[i];
            p1[i] = a1; p2[i] = a2;
            a1 += v1; a2 += v2;
        }
        nck[0] = a2;
    }
    __syncthreads();
    int run = p1[tid];
    int crun = p2[tid];
    for (int i = 0; i < BPT; ++i) {
        int b = b0 + i;
        int binStart = run;
        for (int j = 0; j < 9; ++j) {
            int k = b * 9 + j;
            offsets[k] = run;
            cursor[k]  = run;
            run += counts[k];
        }
        int bc = run - binStart;
        int nc = (bc + CHK - 1) / CHK;
        unsigned int mf = (nc > 1) ? MULTI_FLAG : 0u;
        for (int k2 = 0; k2 < nc; ++k2)
            chunk_info[crun + k2] = (unsigned int)b | ((unsigned int)k2 << 12) | mf;
        crun += nc;
    }
    if (tid == 255) offsets[NKEYS] = run;   // sentinel (global total)
}

// ---------------------------------------------------------------------------
// Bucket walk: records [lo,hi) of one z-bucket, read directly from global
// recs (wave-uniform broadcast loads). 4-record batch ping-pong prefetch.
// PROC semantics identical to R15/R17 (known-good).
template<bool CZ1>
__device__ __forceinline__ void walk_bucket(
    const float* __restrict__ enc, const float4* __restrict__ recs,
    float* tile,
    int lo, int hi, int wzofs, int cx, int cy, int c, int dxm1, int dym1)
{
    if (lo >= hi) return;
    const int last = hi - 1;

    auto LD = [&](int j, float4& R, float& e) {
        int jj = j < last ? j : last;       // sentinel clamp
        R = recs[jj];
        unsigned sp = __float_as_uint(R.x); // wave-uniform (jj scalar)
        e = enc[((sp >> 12) << 4) + c];
    };
    auto PROCF = [&](const float4& Rc, float ev) {
        unsigned pk = __float_as_uint(Rc.x);
        int lx = (int)(pk & 15u) + dxm1;
        int ly = (int)((pk >> 4) & 15u) + dym1;
        if ((unsigned)(lx | ly) < 8u) {
            float wx = cx ? Rc.y : 1.0f - Rc.y;
            float wy = cy ? Rc.z : 1.0f - Rc.z;
            float wz = CZ1 ? Rc.w : 1.0f - Rc.w;
            int off = ((wzofs + (ly << 3) + lx) << 4) + c;
            tile[off] += (wx * wy) * (wz * ev);
        }
    };

    float4 A0, A1, A2, A3, B0, B1, B2, B3;
    float ea0, ea1, ea2, ea3, eb0, eb1, eb2, eb3;
    LD(lo,     A0, ea0); LD(lo + 1, A1, ea1);
    LD(lo + 2, A2, ea2); LD(lo + 3, A3, ea3);
    int g = lo;
    for (;;) {
        LD(g + 4, B0, eb0); LD(g + 5, B1, eb1);
        LD(g + 6, B2, eb2); LD(g + 7, B3, eb3);
        PROCF(A0, ea0);
        if (g + 1 < hi) PROCF(A1, ea1);
        if (g + 2 < hi) PROCF(A2, ea2);
        if (g + 3 < hi) PROCF(A3, ea3);
        g += 4;
        if (g >= hi) break;

        LD(g + 4, A0, ea0); LD(g + 5, A1, ea1);
        LD(g + 6, A2, ea2); LD(g + 7, A3, ea3);
        PROCF(B0, eb0);
        if (g + 1 < hi) PROCF(B1, eb1);
        if (g + 2 < hi) PROCF(B2, eb2);
        if (g + 3 < hi) PROCF(B3, eb3);
        g += 4;
        if (g >= hi) break;
    }
}

// ---------------------------------------------------------------------------
// Pass D: one block (8 z-slab waves) per chunk. Records already z-sorted
// within each bin; bucket boundaries from offsets[], clamped to the chunk.
// Wave w walks buckets w (cz=1) and w+1 (cz=0). Pure walk + flush.
__global__ __launch_bounds__(ACC_THREADS, 8) void accum_kernel(
    const float* __restrict__ enc,
    const int* __restrict__ offsets,
    const float4* __restrict__ recs, const unsigned int* __restrict__ chunk_info,
    const int* __restrict__ nck,
    float* __restrict__ grid)
{
    if ((int)blockIdx.x >= nck[0]) return;
    unsigned int info = chunk_info[blockIdx.x];
    int bin  = (int)(info & 0xFFFu);
    int k    = (int)((info >> 12) & 0x7FFFFu);
    bool multi = (info & MULTI_FLAG) != 0;

    int base9 = bin * 9;
    int binStart = offsets[base9];
    int binEnd   = offsets[base9 + 9];
    int start = binStart + k * CHK;
    int end   = start + CHK; if (end > binEnd) end = binEnd;

    int tx = bin & 15, ty = (bin >> 4) & 15, tz = bin >> 8;
    int gx0 = tx << 3, gy0 = ty << 3, gz0 = tz << 3;

    __shared__ float tile[TILE_FL];   // 32 KB only -> 4 blocks/CU
    int tid = threadIdx.x;
    {
        float4* t4 = (float4*)tile;
        #pragma unroll
        for (int i = tid; i < TILE_FL / 4; i += ACC_THREADS)
            t4[i] = make_float4(0.f, 0.f, 0.f, 0.f);
    }
    __syncthreads();

    // Wave w owns z-layer w. Bucket w: cz=1 (wzv = fz); bucket w+1: cz=0.
    int swz  = __builtin_amdgcn_readfirstlane(tid >> 6);
    int lane = tid & 63;
    int c2   = lane >> 4;               // xy-corner 0..3
    int cx   = c2 & 1, cy = c2 >> 1;
    int c    = lane & 15;               // channel
    int dxm1 = cx - 1, dym1 = cy - 1;
    int wzofs = swz << 6;               // wz * 64 points (scalar)

    int rA = offsets[base9 + swz];
    int rM = offsets[base9 + swz + 1];
    int rB = offsets[base9 + swz + 2];

    int loA = rA > start ? rA : start;
    int hiA = rM < end   ? rM : end;
    int loB = rM > start ? rM : start;
    int hiB = rB < end   ? rB : end;

    walk_bucket<true >(enc, recs, tile, loA, hiA, wzofs, cx, cy, c, dxm1, dym1);
    walk_bucket<false>(enc, recs, tile, loB, hiB, wzofs, cx, cy, c, dxm1, dym1);

    __syncthreads();

    // Flush: contiguous wave-level pattern (lane-adjacent addresses).
    if (!multi) {
        const float4* t4 = (const float4*)tile;
        for (int i = tid; i < TILE_FL / 4; i += ACC_THREADS) {
            float4 v = t4[i];
            if (v.x == 0.f && v.y == 0.f && v.z == 0.f && v.w == 0.f) continue;
            int point = i >> 2;
            int q = (i & 3) << 2;
            int lx = point & 7, ly = (point >> 3) & 7, lz = point >> 6;
            size_t gf = (((size_t)((gz0 + lz) * GH + gy0 + ly)) * GW + gx0 + lx) * GC + q;
            *(float4*)&grid[gf] = v;
        }
    } else {
        for (int idx = tid; idx < TILE_FL; idx += ACC_THREADS) {
            float v = tile[idx];
            if (v == 0.f) continue;
            int point = idx >> 4, cc = idx & 15;
            int lx = point & 7, ly = (point >> 3) & 7, lz = point >> 6;
            unsafeAtomicAdd(
                &grid[(((gz0 + lz) * GH + gy0 + ly) * GW + gx0 + lx) * GC + cc], v);
        }
    }
}

// ---------------------------------------------------------------------------
// Fallback: direct atomic splat (round-1 kernel) if d_ws is too small.
__global__ __launch_bounds__(256) void splat_direct(
    const float* __restrict__ dirs, const float* __restrict__ orig,
    const float* __restrict__ nearv, const float* __restrict__ farv,
    const float* __restrict__ enc,
    float* __restrict__ grid, int n_rays)
{
    int gt = blockIdx.x * blockDim.x + threadIdx.x;
    int group = gt >> 4;
    int c = gt & 15;
    if (group >= n_rays * ST) return;
    int ray = group / ST;
    int s   = group - ray * ST;
    int ix, iy, iz; float fx, fy, fz;
    if (!compute_sample(dirs, orig, nearv, farv, ray, s, ix, iy, iz, fx, fy, fz))
        return;
    float ev = enc[ray * GC + c];
    float gx0 = 1.0f - fx, gy0 = 1.0f - fy, gz0 = 1.0f - fz;
    #pragma unroll
    for (int corner = 0; corner < 8; ++corner) {
        int cx = corner & 1, cy = (corner >> 1) & 1, cz = (corner >> 2) & 1;
        int jx = ix + cx, jy = iy + cy, jz = iz + cz;
        if (jx < 0 || jx >= GW || jy < 0 || jy >= GH || jz < 0 || jz >= GD) continue;
        float w = (cx ? fx : gx0) * (cy ? fy : gy0) * (cz ? fz : gz0);
        unsafeAtomicAdd(&grid[((jz * GH + jy) * GW + jx) * GC + c], w * ev);
    }
}

// ---------------------------------------------------------------------------
extern "C" void kernel_launch(void* const* d_in, const int* in_sizes, int n_in,
                              void* d_out, int out_size, void* d_ws, size_t ws_size,
                              hipStream_t stream) {
    const float* dirs  = (const float*)d_in[0];
    const float* orig  = (const float*)d_in[1];
    const float* nearv = (const float*)d_in[2];
    const float* farv  = (const float*)d_in[3];
    const float* enc   = (const float*)d_in[4];
    float* out = (float*)d_out;

    int n_rays = in_sizes[2];
    int total  = n_rays * ST;

    hipMemsetAsync(out, 0, (size_t)out_size * sizeof(float), stream);

    // Workspace: [counts(NKEYS)|offsets(NKEYS+1)|cursor(NKEYS)|nck|chunk_info|
    //             (align16) recs(cap)]
    int cap = total + total / 2;                 // record capacity (~1.5x)
    int maxck = NBINS + cap / CHK + 2;           // chunk-table bound
    size_t prefix_ints = (size_t)NKEYS * 3 + 1 + 1 + (size_t)maxck;
    prefix_ints = (prefix_ints + 3) & ~(size_t)3;        // align recs to 16 B
    size_t need = prefix_ints * 4 + (size_t)cap * 16;

    if (ws_size < need || n_rays >= (1 << 20)) {
        long long tthreads = (long long)total * 16;
        int blocks = (int)((tthreads + 255) / 256);
        splat_direct<<<blocks, 256, 0, stream>>>(dirs, orig, nearv, farv, enc,
                                                 out, n_rays);
        return;
    }

    int* counts  = (int*)d_ws;
    int* offsets = counts + NKEYS;       // NKEYS+1 (sentinel)
    int* cursor  = offsets + NKEYS + 1;
    int* nck     = cursor + NKEYS;
    unsigned int* chunk_info = (unsigned int*)(nck + 1);
    float4* recs = (float4*)((int*)d_ws + prefix_ints);

    hipMemsetAsync(counts, 0, NKEYS * sizeof(int), stream);
    int sblocks = (total + 255) / 256;
    bin_kernel<false><<<sblocks, 256, 0, stream>>>(
        dirs, orig, nearv, farv, counts, recs, total, cap);
    scan_kernel<<<1, 256, 0, stream>>>(counts, offsets, cursor, chunk_info, nck);
    bin_kernel<true><<<sblocks, 256, 0, stream>>>(
        dirs, orig, nearv, farv, cursor, recs, total, cap);
    accum_kernel<<<maxck, ACC_THREADS, 0, stream>>>(
        enc, offsets, recs, chunk_info, nck, out);
}

// Round 19
// 211.642 us; speedup vs baseline: 1.0934x; 1.0934x over previous
//
#include <hip/hip_runtime.h>

// LightplaneSplatter: trilinear scatter-splat of per-ray encodings (C=16)
// into a (1,128,128,128,16) fp32 grid.
//
// Round 19: hybrid of R17+R18 (accum-only change vs R18).
//   R18 post-mortem: moving the z-sort into scatter was right (-16us on
//   count/scatter), but walking records from GLOBAL regressed accum 118->134
//   (broadcast loads at L2 latency, 2x redundant fetches; 4-deep prefetch
//   covers LDS ~120cy, not global ~200-500cy). Fix: stage the chunk's
//   already-sorted records into LDS via a plain coalesced copy (no
//   histogram/placement/barriers), then R17's verbatim 4-deep LDS walk.
//   bin/scan kernels byte-identical to R18.

#define NS   64
#define NSI  8
#define ST   (NS + NSI)   // 72
#define GD   128
#define GH   128
#define GW   128
#define GC   16
#define DISP_INF 1e-4f

#define NTT   16                    // tiles per axis (8 points each)
#define NBINS (NTT * NTT * NTT)     // 4096
#define NKEYS (NBINS * 9)           // 36864 (bin x z-bucket)
#define TILE_FL (8 * 8 * 8 * GC)    // 8192 floats = 32 KB
#define CHK   1024                  // samples per chunk
#define MULTI_FLAG 0x80000000u
#define ACC_THREADS 512             // 8 waves, one z-layer each

// ---------------------------------------------------------------------------
__device__ __forceinline__ bool compute_sample(
    const float* __restrict__ dirs, const float* __restrict__ orig,
    const float* __restrict__ nearv, const float* __restrict__ farv,
    int ray, int s,
    int& ix, int& iy, int& iz, float& fx, float& fy, float& fz)
{
    float nr = nearv[ray], fr = farv[ray];
    float t;
    if (s < NS) {
        float frac = ((float)s + 0.5f) * (1.0f / (float)NS);
        t = nr + (fr - nr) * frac;
    } else {
        float j    = (float)(s - NS + 1) * (1.0f / (float)NSI);
        float invf = 1.0f / fr;
        float disp = invf + (DISP_INF - invf) * j;
        t = 1.0f / disp;
    }
    float px = orig[ray*3+0] + t * dirs[ray*3+0];
    float py = orig[ray*3+1] + t * dirs[ray*3+1];
    float pz = orig[ray*3+2] + t * dirs[ray*3+2];
    float vx = (px + 1.0f) * 0.5f * 127.0f;
    float vy = (py + 1.0f) * 0.5f * 127.0f;
    float vz = (pz + 1.0f) * 0.5f * 127.0f;
    float bx = floorf(vx), by = floorf(vy), bz = floorf(vz);
    fx = vx - bx; fy = vy - by; fz = vz - bz;
    ix = (int)bx; iy = (int)by; iz = (int)bz;
    return !(ix < -1 || ix > GW - 1 ||
             iy < -1 || iy > GH - 1 ||
             iz < -1 || iz > GD - 1);
}

// Tile range touched by base cell i along one axis (i in [-1, 127]).
__device__ __forceinline__ void tile_range(int i, int& t0, int& t1)
{
    t0 = (i < 0 ? 0 : i) >> 3;
    t1 = (i + 1 > 127 ? 127 : i + 1) >> 3;
}

// ---------------------------------------------------------------------------
// Passes A (WRITE=false: count) and C (WRITE=true: scatter), shared body.
// Per footprint copy: key = bin*9 + zb. Wave-run aggregation: leader does one
// atomicAdd(cursor[key], runLen); for scatter, lanes write contiguous slots.
// Record: float4 { uint pack = ray<<12 | zb<<8 | (ly0+1)<<4 | (lx0+1),
//                  fx, fy, fz }.
template<bool WRITE>
__global__ __launch_bounds__(256) void bin_kernel(
    const float* __restrict__ dirs, const float* __restrict__ orig,
    const float* __restrict__ nearv, const float* __restrict__ farv,
    int* __restrict__ cursor, float4* __restrict__ recs, int total, int cap)
{
    int idx  = blockIdx.x * 256 + threadIdx.x;
    int lane = threadIdx.x & 63;
    bool act = (idx < total);

    int ix = 0, iy = 0, iz = 0; float fx = 0.f, fy = 0.f, fz = 0.f;
    int tx0 = 0, tx1 = -1, ty0 = 0, ty1 = -1, tz0 = 0, tz1 = -1;
    int ray = 0;
    if (act) {
        ray = idx / ST;
        int s = idx - ray * ST;
        if (compute_sample(dirs, orig, nearv, farv, ray, s, ix, iy, iz, fx, fy, fz)) {
            tile_range(ix, tx0, tx1);
            tile_range(iy, ty0, ty1);
            tile_range(iz, tz0, tz1);
        }
    }

    #pragma unroll
    for (int kz = 0; kz < 2; ++kz)
    #pragma unroll
    for (int ky = 0; ky < 2; ++ky)
    #pragma unroll
    for (int kx = 0; kx < 2; ++kx) {
        int tzi = tz0 + kz, tyi = ty0 + ky, txi = tx0 + kx;
        bool valid = (tzi <= tz1 && tyi <= ty1 && txi <= tx1);
        int zb  = iz - (tzi << 3) + 1;          // in [0,8] when valid
        int key = valid ? ((tzi * NTT + tyi) * NTT + txi) * 9 + zb : -1;

        // Run detection: leader = first lane of a maximal same-key run.
        int prev = __shfl_up(key, 1, 64);
        bool leader = (lane == 0) || (key != prev);
        unsigned long long lm = __ballot(leader);
        unsigned long long below = lm & ((2ull << lane) - 1ull);
        int lead = 63 - __clzll(below);

        int base = 0;
        if (leader && key >= 0) {
            unsigned long long rest = (lane == 63) ? 0ull : (lm >> (lane + 1));
            int next = rest ? (lane + 1 + (__ffsll((long long)rest) - 1)) : 64;
            base = atomicAdd(&cursor[key], next - lane);
        }
        if (WRITE) {
            base = __shfl(base, lead, 64);
            if (key >= 0) {
                int slot = base + (lane - lead);
                if (slot < cap) {
                    unsigned int pk = ((unsigned int)ray << 12)
                                    | ((unsigned int)zb << 8)
                                    | ((unsigned int)(iy - (tyi << 3) + 1) << 4)
                                    |  (unsigned int)(ix - (txi << 3) + 1);
                    recs[slot] = make_float4(__uint_as_float(pk), fx, fy, fz);
                }
            }
        }
    }
}

// ---------------------------------------------------------------------------
// Pass B: scan 36864 key-counts -> offsets/cursor; emit per-bin chunk table.
__global__ __launch_bounds__(256) void scan_kernel(
    const int* __restrict__ counts, int* __restrict__ offsets,
    int* __restrict__ cursor, unsigned int* __restrict__ chunk_info,
    int* __restrict__ nck)
{
    __shared__ int p1[256], p2[256];
    const int BPT = NBINS / 256;  // 16 bins (144 keys) per thread
    int tid = threadIdx.x;
    int b0 = tid * BPT;
    int s1 = 0, s2 = 0;
    for (int i = 0; i < BPT; ++i) {
        int bc = 0;
        for (int j = 0; j < 9; ++j) bc += counts[(b0 + i) * 9 + j];
        s1 += bc;
        s2 += (bc + CHK - 1) / CHK;
    }
    p1[tid] = s1; p2[tid] = s2;
    __syncthreads();
    if (tid == 0) {
        int a1 = 0, a2 = 0;
        for (int i = 0; i < 256; ++i) {
            int v1 = p1[i], v2 = p2[i];
            p1[i] = a1; p2[i] = a2;
            a1 += v1; a2 += v2;
        }
        nck[0] = a2;
    }
    __syncthreads();
    int run = p1[tid];
    int crun = p2[tid];
    for (int i = 0; i < BPT; ++i) {
        int b = b0 + i;
        int binStart = run;
        for (int j = 0; j < 9; ++j) {
            int k = b * 9 + j;
            offsets[k] = run;
            cursor[k]  = run;
            run += counts[k];
        }
        int bc = run - binStart;
        int nc = (bc + CHK - 1) / CHK;
        unsigned int mf = (nc > 1) ? MULTI_FLAG : 0u;
        for (int k2 = 0; k2 < nc; ++k2)
            chunk_info[crun + k2] = (unsigned int)b | ((unsigned int)k2 << 12) | mf;
        crun += nc;
    }
    if (tid == 255) offsets[NKEYS] = run;   // sentinel (global total)
}

// ---------------------------------------------------------------------------
// Bucket walk: records [lo,hi) of one z-bucket in LDS srec (chunk-local
// coords). 4-record batch ping-pong prefetch; PROC semantics = R15/R17.
template<bool CZ1>
__device__ __forceinline__ void walk_bucket(
    const float* __restrict__ enc, const float4* srec, float* tile,
    int lo, int hi, int wzofs, int cx, int cy, int c, int dxm1, int dym1)
{
    if (lo >= hi) return;
    const int last = hi - 1;

    auto LD = [&](int j, float4& R, float& e) {
        int jj = j < last ? j : last;       // sentinel clamp
        R = srec[jj];
        unsigned sp = __float_as_uint(R.x); // wave-uniform (jj scalar)
        e = enc[((sp >> 12) << 4) + c];
    };
    auto PROCF = [&](const float4& Rc, float ev) {
        unsigned pk = __float_as_uint(Rc.x);
        int lx = (int)(pk & 15u) + dxm1;
        int ly = (int)((pk >> 4) & 15u) + dym1;
        if ((unsigned)(lx | ly) < 8u) {
            float wx = cx ? Rc.y : 1.0f - Rc.y;
            float wy = cy ? Rc.z : 1.0f - Rc.z;
            float wz = CZ1 ? Rc.w : 1.0f - Rc.w;
            int off = ((wzofs + (ly << 3) + lx) << 4) + c;
            tile[off] += (wx * wy) * (wz * ev);
        }
    };

    float4 A0, A1, A2, A3, B0, B1, B2, B3;
    float ea0, ea1, ea2, ea3, eb0, eb1, eb2, eb3;
    LD(lo,     A0, ea0); LD(lo + 1, A1, ea1);
    LD(lo + 2, A2, ea2); LD(lo + 3, A3, ea3);
    int g = lo;
    for (;;) {
        LD(g + 4, B0, eb0); LD(g + 5, B1, eb1);
        LD(g + 6, B2, eb2); LD(g + 7, B3, eb3);
        PROCF(A0, ea0);
        if (g + 1 < hi) PROCF(A1, ea1);
        if (g + 2 < hi) PROCF(A2, ea2);
        if (g + 3 < hi) PROCF(A3, ea3);
        g += 4;
        if (g >= hi) break;

        LD(g + 4, A0, ea0); LD(g + 5, A1, ea1);
        LD(g + 6, A2, ea2); LD(g + 7, A3, ea3);
        PROCF(B0, eb0);
        if (g + 1 < hi) PROCF(B1, eb1);
        if (g + 2 < hi) PROCF(B2, eb2);
        if (g + 3 < hi) PROCF(B3, eb3);
        g += 4;
        if (g >= hi) break;
    }
}

// ---------------------------------------------------------------------------
// Pass D: one block (8 z-slab waves) per chunk. Records arrive z-sorted;
// stage chunk into LDS with a plain coalesced copy, then walk buckets from
// LDS. Wave w walks buckets w (cz=1) and w+1 (cz=0).
__global__ __launch_bounds__(ACC_THREADS, 6) void accum_kernel(
    const float* __restrict__ enc,
    const int* __restrict__ offsets,
    const float4* __restrict__ recs, const unsigned int* __restrict__ chunk_info,
    const int* __restrict__ nck,
    float* __restrict__ grid)
{
    if ((int)blockIdx.x >= nck[0]) return;
    unsigned int info = chunk_info[blockIdx.x];
    int bin  = (int)(info & 0xFFFu);
    int k    = (int)((info >> 12) & 0x7FFFFu);
    bool multi = (info & MULTI_FLAG) != 0;

    int base9 = bin * 9;
    int binStart = offsets[base9];
    int binEnd   = offsets[base9 + 9];
    int start = binStart + k * CHK;
    int end   = start + CHK; if (end > binEnd) end = binEnd;
    int n = end - start;

    int tx = bin & 15, ty = (bin >> 4) & 15, tz = bin >> 8;
    int gx0 = tx << 3, gy0 = ty << 3, gz0 = tz << 3;

    __shared__ float  tile[TILE_FL];   // 32 KB
    __shared__ float4 srec[CHK];       // 16 KB

    int tid = threadIdx.x;
    {
        float4* t4 = (float4*)tile;
        #pragma unroll
        for (int i = tid; i < TILE_FL / 4; i += ACC_THREADS)
            t4[i] = make_float4(0.f, 0.f, 0.f, 0.f);
    }
    // Stage chunk records (already z-sorted) into LDS, coalesced.
    for (int i = tid; i < n; i += ACC_THREADS)
        srec[i] = recs[start + i];
    __syncthreads();

    // Wave w owns z-layer w. Bucket w: cz=1 (wzv = fz); bucket w+1: cz=0.
    int swz  = __builtin_amdgcn_readfirstlane(tid >> 6);
    int lane = tid & 63;
    int c2   = lane >> 4;               // xy-corner 0..3
    int cx   = c2 & 1, cy = c2 >> 1;
    int c    = lane & 15;               // channel
    int dxm1 = cx - 1, dym1 = cy - 1;
    int wzofs = swz << 6;               // wz * 64 points (scalar)

    int rA = offsets[base9 + swz];
    int rM = offsets[base9 + swz + 1];
    int rB = offsets[base9 + swz + 2];

    // Clamp to chunk and rebase to chunk-local srec coords.
    int loA = (rA > start ? rA : start) - start;
    int hiA = (rM < end   ? rM : end)   - start;
    int loB = (rM > start ? rM : start) - start;
    int hiB = (rB < end   ? rB : end)   - start;

    walk_bucket<true >(enc, srec, tile, loA, hiA, wzofs, cx, cy, c, dxm1, dym1);
    walk_bucket<false>(enc, srec, tile, loB, hiB, wzofs, cx, cy, c, dxm1, dym1);

    __syncthreads();

    // Flush: contiguous wave-level pattern (lane-adjacent addresses).
    if (!multi) {
        const float4* t4 = (const float4*)tile;
        for (int i = tid; i < TILE_FL / 4; i += ACC_THREADS) {
            float4 v = t4[i];
            if (v.x == 0.f && v.y == 0.f && v.z == 0.f && v.w == 0.f) continue;
            int point = i >> 2;
            int q = (i & 3) << 2;
            int lx = point & 7, ly = (point >> 3) & 7, lz = point >> 6;
            size_t gf = (((size_t)((gz0 + lz) * GH + gy0 + ly)) * GW + gx0 + lx) * GC + q;
            *(float4*)&grid[gf] = v;
        }
    } else {
        for (int idx = tid; idx < TILE_FL; idx += ACC_THREADS) {
            float v = tile[idx];
            if (v == 0.f) continue;
            int point = idx >> 4, cc = idx & 15;
            int lx = point & 7, ly = (point >> 3) & 7, lz = point >> 6;
            unsafeAtomicAdd(
                &grid[(((gz0 + lz) * GH + gy0 + ly) * GW + gx0 + lx) * GC + cc], v);
        }
    }
}

// ---------------------------------------------------------------------------
// Fallback: direct atomic splat (round-1 kernel) if d_ws is too small.
__global__ __launch_bounds__(256) void splat_direct(
    const float* __restrict__ dirs, const float* __restrict__ orig,
    const float* __restrict__ nearv, const float* __restrict__ farv,
    const float* __restrict__ enc,
    float* __restrict__ grid, int n_rays)
{
    int gt = blockIdx.x * blockDim.x + threadIdx.x;
    int group = gt >> 4;
    int c = gt & 15;
    if (group >= n_rays * ST) return;
    int ray = group / ST;
    int s   = group - ray * ST;
    int ix, iy, iz; float fx, fy, fz;
    if (!compute_sample(dirs, orig, nearv, farv, ray, s, ix, iy, iz, fx, fy, fz))
        return;
    float ev = enc[ray * GC + c];
    float gx0 = 1.0f - fx, gy0 = 1.0f - fy, gz0 = 1.0f - fz;
    #pragma unroll
    for (int corner = 0; corner < 8; ++corner) {
        int cx = corner & 1, cy = (corner >> 1) & 1, cz = (corner >> 2) & 1;
        int jx = ix + cx, jy = iy + cy, jz = iz + cz;
        if (jx < 0 || jx >= GW || jy < 0 || jy >= GD) continue;
        if (jy >= GH || jz < 0 || jz >= GD) continue;
        float w = (cx ? fx : gx0) * (cy ? fy : gy0) * (cz ? fz : gz0);
        unsafeAtomicAdd(&grid[((jz * GH + jy) * GW + jx) * GC + c], w * ev);
    }
}

// ---------------------------------------------------------------------------
extern "C" void kernel_launch(void* const* d_in, const int* in_sizes, int n_in,
                              void* d_out, int out_size, void* d_ws, size_t ws_size,
                              hipStream_t stream) {
    const float* dirs  = (const float*)d_in[0];
    const float* orig  = (const float*)d_in[1];
    const float* nearv = (const float*)d_in[2];
    const float* farv  = (const float*)d_in[3];
    const float* enc   = (const float*)d_in[4];
    float* out = (float*)d_out;

    int n_rays = in_sizes[2];
    int total  = n_rays * ST;

    hipMemsetAsync(out, 0, (size_t)out_size * sizeof(float), stream);

    // Workspace: [counts(NKEYS)|offsets(NKEYS+1)|cursor(NKEYS)|nck|chunk_info|
    //             (align16) recs(cap)]
    int cap = total + total / 2;                 // record capacity (~1.5x)
    int maxck = NBINS + cap / CHK + 2;           // chunk-table bound
    size_t prefix_ints = (size_t)NKEYS * 3 + 1 + 1 + (size_t)maxck;
    prefix_ints = (prefix_ints + 3) & ~(size_t)3;        // align recs to 16 B
    size_t need = prefix_ints * 4 + (size_t)cap * 16;

    if (ws_size < need || n_rays >= (1 << 20)) {
        long long tthreads = (long long)total * 16;
        int blocks = (int)((tthreads + 255) / 256);
        splat_direct<<<blocks, 256, 0, stream>>>(dirs, orig, nearv, farv, enc,
                                                 out, n_rays);
        return;
    }

    int* counts  = (int*)d_ws;
    int* offsets = counts + NKEYS;       // NKEYS+1 (sentinel)
    int* cursor  = offsets + NKEYS + 1;
    int* nck     = cursor + NKEYS;
    unsigned int* chunk_info = (unsigned int*)(nck + 1);
    float4* recs = (float4*)((int*)d_ws + prefix_ints);

    hipMemsetAsync(counts, 0, NKEYS * sizeof(int), stream);
    int sblocks = (total + 255) / 256;
    bin_kernel<false><<<sblocks, 256, 0, stream>>>(
        dirs, orig, nearv, farv, counts, recs, total, cap);
    scan_kernel<<<1, 256, 0, stream>>>(counts, offsets, cursor, chunk_info, nck);
    bin_kernel<true><<<sblocks, 256, 0, stream>>>(
        dirs, orig, nearv, farv, cursor, recs, total, cap);
    accum_kernel<<<maxck, ACC_THREADS, 0, stream>>>(
        enc, offsets, recs, chunk_info, nck, out);
}

// Round 20
// 199.184 us; speedup vs baseline: 1.1618x; 1.0625x over previous
//
#include <hip/hip_runtime.h>

// LightplaneSplatter: trilinear scatter-splat of per-ray encodings (C=16)
// into a (1,128,128,128,16) fp32 grid.
//
// Round 20: eliminate the 128 MiB grid memset (vs R19, accum walk untouched).
//   Tiles partition the output exactly, so single-chunk bins' flush writes
//   the FULL tile unconditionally (zeros included) -- no pre-zero needed.
//   Only empty bins and multi-chunk bins (atomic flush) need zeroing; a
//   zero_fill kernel (one block/bin, early-exit on single-chunk bins) covers
//   those after scan. Grid writes: 225 MB (memset+sparse flush) -> ~140 MB.
//   bin/scan/walk byte-identical to R19.

#define NS   64
#define NSI  8
#define ST   (NS + NSI)   // 72
#define GD   128
#define GH   128
#define GW   128
#define GC   16
#define DISP_INF 1e-4f

#define NTT   16                    // tiles per axis (8 points each)
#define NBINS (NTT * NTT * NTT)     // 4096
#define NKEYS (NBINS * 9)           // 36864 (bin x z-bucket)
#define TILE_FL (8 * 8 * 8 * GC)    // 8192 floats = 32 KB
#define CHK   1024                  // samples per chunk
#define MULTI_FLAG 0x80000000u
#define ACC_THREADS 512             // 8 waves, one z-layer each

// ---------------------------------------------------------------------------
__device__ __forceinline__ bool compute_sample(
    const float* __restrict__ dirs, const float* __restrict__ orig,
    const float* __restrict__ nearv, const float* __restrict__ farv,
    int ray, int s,
    int& ix, int& iy, int& iz, float& fx, float& fy, float& fz)
{
    float nr = nearv[ray], fr = farv[ray];
    float t;
    if (s < NS) {
        float frac = ((float)s + 0.5f) * (1.0f / (float)NS);
        t = nr + (fr - nr) * frac;
    } else {
        float j    = (float)(s - NS + 1) * (1.0f / (float)NSI);
        float invf = 1.0f / fr;
        float disp = invf + (DISP_INF - invf) * j;
        t = 1.0f / disp;
    }
    float px = orig[ray*3+0] + t * dirs[ray*3+0];
    float py = orig[ray*3+1] + t * dirs[ray*3+1];
    float pz = orig[ray*3+2] + t * dirs[ray*3+2];
    float vx = (px + 1.0f) * 0.5f * 127.0f;
    float vy = (py + 1.0f) * 0.5f * 127.0f;
    float vz = (pz + 1.0f) * 0.5f * 127.0f;
    float bx = floorf(vx), by = floorf(vy), bz = floorf(vz);
    fx = vx - bx; fy = vy - by; fz = vz - bz;
    ix = (int)bx; iy = (int)by; iz = (int)bz;
    return !(ix < -1 || ix > GW - 1 ||
             iy < -1 || iy > GH - 1 ||
             iz < -1 || iz > GD - 1);
}

// Tile range touched by base cell i along one axis (i in [-1, 127]).
__device__ __forceinline__ void tile_range(int i, int& t0, int& t1)
{
    t0 = (i < 0 ? 0 : i) >> 3;
    t1 = (i + 1 > 127 ? 127 : i + 1) >> 3;
}

// ---------------------------------------------------------------------------
// Passes A (WRITE=false: count) and C (WRITE=true: scatter), shared body.
// Per footprint copy: key = bin*9 + zb. Wave-run aggregation: leader does one
// atomicAdd(cursor[key], runLen); for scatter, lanes write contiguous slots.
// Record: float4 { uint pack = ray<<12 | zb<<8 | (ly0+1)<<4 | (lx0+1),
//                  fx, fy, fz }.
template<bool WRITE>
__global__ __launch_bounds__(256) void bin_kernel(
    const float* __restrict__ dirs, const float* __restrict__ orig,
    const float* __restrict__ nearv, const float* __restrict__ farv,
    int* __restrict__ cursor, float4* __restrict__ recs, int total, int cap)
{
    int idx  = blockIdx.x * 256 + threadIdx.x;
    int lane = threadIdx.x & 63;
    bool act = (idx < total);

    int ix = 0, iy = 0, iz = 0; float fx = 0.f, fy = 0.f, fz = 0.f;
    int tx0 = 0, tx1 = -1, ty0 = 0, ty1 = -1, tz0 = 0, tz1 = -1;
    int ray = 0;
    if (act) {
        ray = idx / ST;
        int s = idx - ray * ST;
        if (compute_sample(dirs, orig, nearv, farv, ray, s, ix, iy, iz, fx, fy, fz)) {
            tile_range(ix, tx0, tx1);
            tile_range(iy, ty0, ty1);
            tile_range(iz, tz0, tz1);
        }
    }

    #pragma unroll
    for (int kz = 0; kz < 2; ++kz)
    #pragma unroll
    for (int ky = 0; ky < 2; ++ky)
    #pragma unroll
    for (int kx = 0; kx < 2; ++kx) {
        int tzi = tz0 + kz, tyi = ty0 + ky, txi = tx0 + kx;
        bool valid = (tzi <= tz1 && tyi <= ty1 && txi <= tx1);
        int zb  = iz - (tzi << 3) + 1;          // in [0,8] when valid
        int key = valid ? ((tzi * NTT + tyi) * NTT + txi) * 9 + zb : -1;

        // Run detection: leader = first lane of a maximal same-key run.
        int prev = __shfl_up(key, 1, 64);
        bool leader = (lane == 0) || (key != prev);
        unsigned long long lm = __ballot(leader);
        unsigned long long below = lm & ((2ull << lane) - 1ull);
        int lead = 63 - __clzll(below);

        int base = 0;
        if (leader && key >= 0) {
            unsigned long long rest = (lane == 63) ? 0ull : (lm >> (lane + 1));
            int next = rest ? (lane + 1 + (__ffsll((long long)rest) - 1)) : 64;
            base = atomicAdd(&cursor[key], next - lane);
        }
        if (WRITE) {
            base = __shfl(base, lead, 64);
            if (key >= 0) {
                int slot = base + (lane - lead);
                if (slot < cap) {
                    unsigned int pk = ((unsigned int)ray << 12)
                                    | ((unsigned int)zb << 8)
                                    | ((unsigned int)(iy - (tyi << 3) + 1) << 4)
                                    |  (unsigned int)(ix - (txi << 3) + 1);
                    recs[slot] = make_float4(__uint_as_float(pk), fx, fy, fz);
                }
            }
        }
    }
}

// ---------------------------------------------------------------------------
// Pass B: scan 36864 key-counts -> offsets/cursor; emit per-bin chunk table.
__global__ __launch_bounds__(256) void scan_kernel(
    const int* __restrict__ counts, int* __restrict__ offsets,
    int* __restrict__ cursor, unsigned int* __restrict__ chunk_info,
    int* __restrict__ nck)
{
    __shared__ int p1[256], p2[256];
    const int BPT = NBINS / 256;  // 16 bins (144 keys) per thread
    int tid = threadIdx.x;
    int b0 = tid * BPT;
    int s1 = 0, s2 = 0;
    for (int i = 0; i < BPT; ++i) {
        int bc = 0;
        for (int j = 0; j < 9; ++j) bc += counts[(b0 + i) * 9 + j];
        s1 += bc;
        s2 += (bc + CHK - 1) / CHK;
    }
    p1[tid] = s1; p2[tid] = s2;
    __syncthreads();
    if (tid == 0) {
        int a1 = 0, a2 = 0;
        for (int i = 0; i < 256; ++i) {
            int v1 = p1[i], v2 = p2[i];
            p1[i] = a1; p2[i] = a2;
            a1 += v1; a2 += v2;
        }
        nck[0] = a2;
    }
    __syncthreads();
    int run = p1[tid];
    int crun = p2[tid];
    for (int i = 0; i < BPT; ++i) {
        int b = b0 + i;
        int binStart = run;
        for (int j = 0; j < 9; ++j) {
            int k = b * 9 + j;
            offsets[k] = run;
            cursor[k]  = run;
            run += counts[k];
        }
        int bc = run - binStart;
        int nc = (bc + CHK - 1) / CHK;
        unsigned int mf = (nc > 1) ? MULTI_FLAG : 0u;
        for (int k2 = 0; k2 < nc; ++k2)
            chunk_info[crun + k2] = (unsigned int)b | ((unsigned int)k2 << 12) | mf;
        crun += nc;
    }
    if (tid == 255) offsets[NKEYS] = run;   // sentinel (global total)
}

// ---------------------------------------------------------------------------
// Zero-fill: one block per bin; zero the bin's 8^3x16 region iff the bin is
// EMPTY (no flush will write it) or MULTI-chunk (atomic flush needs zeroed
// base). Single-chunk bins are fully written by accum's plain-store flush.
__global__ __launch_bounds__(256) void zero_fill(
    const int* __restrict__ offsets, float* __restrict__ grid)
{
    int bin = blockIdx.x;
    int bc = offsets[bin * 9 + 9] - offsets[bin * 9];
    if (bc > 0 && bc <= CHK) return;     // single-chunk bin
    int tx = bin & 15, ty = (bin >> 4) & 15, tz = bin >> 8;
    int gx0 = tx << 3, gy0 = ty << 3, gz0 = tz << 3;
    float4 z = make_float4(0.f, 0.f, 0.f, 0.f);
    for (int i = threadIdx.x; i < TILE_FL / 4; i += 256) {
        int point = i >> 2;
        int q = (i & 3) << 2;
        int lx = point & 7, ly = (point >> 3) & 7, lz = point >> 6;
        size_t gf = (((size_t)((gz0 + lz) * GH + gy0 + ly)) * GW + gx0 + lx) * GC + q;
        *(float4*)&grid[gf] = z;
    }
}

// ---------------------------------------------------------------------------
// Bucket walk: records [lo,hi) of one z-bucket in LDS srec (chunk-local
// coords). 4-record batch ping-pong prefetch; PROC semantics = R15/R17.
template<bool CZ1>
__device__ __forceinline__ void walk_bucket(
    const float* __restrict__ enc, const float4* srec, float* tile,
    int lo, int hi, int wzofs, int cx, int cy, int c, int dxm1, int dym1)
{
    if (lo >= hi) return;
    const int last = hi - 1;

    auto LD = [&](int j, float4& R, float& e) {
        int jj = j < last ? j : last;       // sentinel clamp
        R = srec[jj];
        unsigned sp = __float_as_uint(R.x); // wave-uniform (jj scalar)
        e = enc[((sp >> 12) << 4) + c];
    };
    auto PROCF = [&](const float4& Rc, float ev) {
        unsigned pk = __float_as_uint(Rc.x);
        int lx = (int)(pk & 15u) + dxm1;
        int ly = (int)((pk >> 4) & 15u) + dym1;
        if ((unsigned)(lx | ly) < 8u) {
            float wx = cx ? Rc.y : 1.0f - Rc.y;
            float wy = cy ? Rc.z : 1.0f - Rc.z;
            float wz = CZ1 ? Rc.w : 1.0f - Rc.w;
            int off = ((wzofs + (ly << 3) + lx) << 4) + c;
            tile[off] += (wx * wy) * (wz * ev);
        }
    };

    float4 A0, A1, A2, A3, B0, B1, B2, B3;
    float ea0, ea1, ea2, ea3, eb0, eb1, eb2, eb3;
    LD(lo,     A0, ea0); LD(lo + 1, A1, ea1);
    LD(lo + 2, A2, ea2); LD(lo + 3, A3, ea3);
    int g = lo;
    for (;;) {
        LD(g + 4, B0, eb0); LD(g + 5, B1, eb1);
        LD(g + 6, B2, eb2); LD(g + 7, B3, eb3);
        PROCF(A0, ea0);
        if (g + 1 < hi) PROCF(A1, ea1);
        if (g + 2 < hi) PROCF(A2, ea2);
        if (g + 3 < hi) PROCF(A3, ea3);
        g += 4;
        if (g >= hi) break;

        LD(g + 4, A0, ea0); LD(g + 5, A1, ea1);
        LD(g + 6, A2, ea2); LD(g + 7, A3, ea3);
        PROCF(B0, eb0);
        if (g + 1 < hi) PROCF(B1, eb1);
        if (g + 2 < hi) PROCF(B2, eb2);
        if (g + 3 < hi) PROCF(B3, eb3);
        g += 4;
        if (g >= hi) break;
    }
}

// ---------------------------------------------------------------------------
// Pass D: one block (8 z-slab waves) per chunk. Records arrive z-sorted;
// stage chunk into LDS with a plain coalesced copy, then walk buckets from
// LDS. Wave w walks buckets w (cz=1) and w+1 (cz=0).
__global__ __launch_bounds__(ACC_THREADS, 6) void accum_kernel(
    const float* __restrict__ enc,
    const int* __restrict__ offsets,
    const float4* __restrict__ recs, const unsigned int* __restrict__ chunk_info,
    const int* __restrict__ nck,
    float* __restrict__ grid)
{
    if ((int)blockIdx.x >= nck[0]) return;
    unsigned int info = chunk_info[blockIdx.x];
    int bin  = (int)(info & 0xFFFu);
    int k    = (int)((info >> 12) & 0x7FFFFu);
    bool multi = (info & MULTI_FLAG) != 0;

    int base9 = bin * 9;
    int binStart = offsets[base9];
    int binEnd   = offsets[base9 + 9];
    int start = binStart + k * CHK;
    int end   = start + CHK; if (end > binEnd) end = binEnd;
    int n = end - start;

    int tx = bin & 15, ty = (bin >> 4) & 15, tz = bin >> 8;
    int gx0 = tx << 3, gy0 = ty << 3, gz0 = tz << 3;

    __shared__ float  tile[TILE_FL];   // 32 KB
    __shared__ float4 srec[CHK];       // 16 KB

    int tid = threadIdx.x;
    {
        float4* t4 = (float4*)tile;
        #pragma unroll
        for (int i = tid; i < TILE_FL / 4; i += ACC_THREADS)
            t4[i] = make_float4(0.f, 0.f, 0.f, 0.f);
    }
    // Stage chunk records (already z-sorted) into LDS, coalesced.
    for (int i = tid; i < n; i += ACC_THREADS)
        srec[i] = recs[start + i];
    __syncthreads();

    // Wave w owns z-layer w. Bucket w: cz=1 (wzv = fz); bucket w+1: cz=0.
    int swz  = __builtin_amdgcn_readfirstlane(tid >> 6);
    int lane = tid & 63;
    int c2   = lane >> 4;               // xy-corner 0..3
    int cx   = c2 & 1, cy = c2 >> 1;
    int c    = lane & 15;               // channel
    int dxm1 = cx - 1, dym1 = cy - 1;
    int wzofs = swz << 6;               // wz * 64 points (scalar)

    int rA = offsets[base9 + swz];
    int rM = offsets[base9 + swz + 1];
    int rB = offsets[base9 + swz + 2];

    // Clamp to chunk and rebase to chunk-local srec coords.
    int loA = (rA > start ? rA : start) - start;
    int hiA = (rM < end   ? rM : end)   - start;
    int loB = (rM > start ? rM : start) - start;
    int hiB = (rB < end   ? rB : end)   - start;

    walk_bucket<true >(enc, srec, tile, loA, hiA, wzofs, cx, cy, c, dxm1, dym1);
    walk_bucket<false>(enc, srec, tile, loB, hiB, wzofs, cx, cy, c, dxm1, dym1);

    __syncthreads();

    // Flush. Single-chunk tile: unconditional full-tile store (zeros too --
    // this replaces the global memset for these regions). Multi: zero-skipped
    // atomics onto the zero_fill'ed base.
    if (!multi) {
        const float4* t4 = (const float4*)tile;
        for (int i = tid; i < TILE_FL / 4; i += ACC_THREADS) {
            float4 v = t4[i];
            int point = i >> 2;
            int q = (i & 3) << 2;
            int lx = point & 7, ly = (point >> 3) & 7, lz = point >> 6;
            size_t gf = (((size_t)((gz0 + lz) * GH + gy0 + ly)) * GW + gx0 + lx) * GC + q;
            *(float4*)&grid[gf] = v;
        }
    } else {
        for (int idx = tid; idx < TILE_FL; idx += ACC_THREADS) {
            float v = tile[idx];
            if (v == 0.f) continue;
            int point = idx >> 4, cc = idx & 15;
            int lx = point & 7, ly = (point >> 3) & 7, lz = point >> 6;
            unsafeAtomicAdd(
                &grid[(((gz0 + lz) * GH + gy0 + ly) * GW + gx0 + lx) * GC + cc], v);
        }
    }
}

// ---------------------------------------------------------------------------
// Fallback: direct atomic splat (round-1 kernel) if d_ws is too small.
__global__ __launch_bounds__(256) void splat_direct(
    const float* __restrict__ dirs, const float* __restrict__ orig,
    const float* __restrict__ nearv, const float* __restrict__ farv,
    const float* __restrict__ enc,
    float* __restrict__ grid, int n_rays)
{
    int gt = blockIdx.x * blockDim.x + threadIdx.x;
    int group = gt >> 4;
    int c = gt & 15;
    if (group >= n_rays * ST) return;
    int ray = group / ST;
    int s   = group - ray * ST;
    int ix, iy, iz; float fx, fy, fz;
    if (!compute_sample(dirs, orig, nearv, farv, ray, s, ix, iy, iz, fx, fy, fz))
        return;
    float ev = enc[ray * GC + c];
    float gx0 = 1.0f - fx, gy0 = 1.0f - fy, gz0 = 1.0f - fz;
    #pragma unroll
    for (int corner = 0; corner < 8; ++corner) {
        int cx = corner & 1, cy = (corner >> 1) & 1, cz = (corner >> 2) & 1;
        int jx = ix + cx, jy = iy + cy, jz = iz + cz;
        if (jx < 0 || jx >= GW || jy < 0 || jy >= GH || jz < 0 || jz >= GD) continue;
        float w = (cx ? fx : gx0) * (cy ? fy : gy0) * (cz ? fz : gz0);
        unsafeAtomicAdd(&grid[((jz * GH + jy) * GW + jx) * GC + c], w * ev);
    }
}

// ---------------------------------------------------------------------------
extern "C" void kernel_launch(void* const* d_in, const int* in_sizes, int n_in,
                              void* d_out, int out_size, void* d_ws, size_t ws_size,
                              hipStream_t stream) {
    const float* dirs  = (const float*)d_in[0];
    const float* orig  = (const float*)d_in[1];
    const float* nearv = (const float*)d_in[2];
    const float* farv  = (const float*)d_in[3];
    const float* enc   = (const float*)d_in[4];
    float* out = (float*)d_out;

    int n_rays = in_sizes[2];
    int total  = n_rays * ST;

    // Workspace: [counts(NKEYS)|offsets(NKEYS+1)|cursor(NKEYS)|nck|chunk_info|
    //             (align16) recs(cap)]
    int cap = total + total / 2;                 // record capacity (~1.5x)
    int maxck = NBINS + cap / CHK + 2;           // chunk-table bound
    size_t prefix_ints = (size_t)NKEYS * 3 + 1 + 1 + (size_t)maxck;
    prefix_ints = (prefix_ints + 3) & ~(size_t)3;        // align recs to 16 B
    size_t need = prefix_ints * 4 + (size_t)cap * 16;

    if (ws_size < need || n_rays >= (1 << 20)) {
        hipMemsetAsync(out, 0, (size_t)out_size * sizeof(float), stream);
        long long tthreads = (long long)total * 16;
        int blocks = (int)((tthreads + 255) / 256);
        splat_direct<<<blocks, 256, 0, stream>>>(dirs, orig, nearv, farv, enc,
                                                 out, n_rays);
        return;
    }

    int* counts  = (int*)d_ws;
    int* offsets = counts + NKEYS;       // NKEYS+1 (sentinel)
    int* cursor  = offsets + NKEYS + 1;
    int* nck     = cursor + NKEYS;
    unsigned int* chunk_info = (unsigned int*)(nck + 1);
    float4* recs = (float4*)((int*)d_ws + prefix_ints);

    hipMemsetAsync(counts, 0, NKEYS * sizeof(int), stream);
    int sblocks = (total + 255) / 256;
    bin_kernel<false><<<sblocks, 256, 0, stream>>>(
        dirs, orig, nearv, farv, counts, recs, total, cap);
    scan_kernel<<<1, 256, 0, stream>>>(counts, offsets, cursor, chunk_info, nck);
    zero_fill<<<NBINS, 256, 0, stream>>>(offsets, out);
    bin_kernel<true><<<sblocks, 256, 0, stream>>>(
        dirs, orig, nearv, farv, cursor, recs, total, cap);
    accum_kernel<<<maxck, ACC_THREADS, 0, stream>>>(
        enc, offsets, recs, chunk_info, nck, out);
}